// Round 1
// baseline (225.629 us; speedup 1.0000x reference)
//
#include <hip/hip_runtime.h>

#define LRELU_ALPHA 0.2f

typedef __bf16 bf16x8 __attribute__((ext_vector_type(8)));
typedef unsigned short u16;
typedef unsigned short u16x8 __attribute__((ext_vector_type(8)));
typedef float f32x4 __attribute__((ext_vector_type(4)));
typedef int int4v __attribute__((ext_vector_type(4)));

__device__ __forceinline__ u16 f2bf(float f) {
  unsigned int u = __float_as_uint(f);
  u += 0x7fffu + ((u >> 16) & 1u);   // RNE
  return (u16)(u >> 16);
}

// ---------------- kernel 1: WbT[o][i] = bf16(W[i][o]) ----------------
__global__ __launch_bounds__(256) void wcast(const float* __restrict__ W,
                                             u16* __restrict__ WbT) {
  int idx = blockIdx.x * 256 + threadIdx.x;            // 65536
  WbT[idx] = f2bf(W[(idx & 255) * 256 + (idx >> 8)]);
}

// ---------------- kernel 2: Hh = bf16(h) @ W  (M=16384,K=256,N=256) --
// block: 256 thr / 4 waves, 64 rows x 256 cols per block, grid 256.
__global__ __launch_bounds__(256) void gemm1(const float* __restrict__ h,
                                             const u16* __restrict__ WbT,
                                             float* __restrict__ Hh,
                                             u16* __restrict__ HhT) {
  const int tid = threadIdx.x, bid = blockIdx.x;
  const int l = tid & 63, w = tid >> 6;
  const int lr = l & 15;              // frag row (A) / col (B)
  const int lk = (l >> 4) << 3;       // k offset within 32
  const int rowA = bid * 64 + 16 * w + lr;
  const float* hrow = h + (size_t)rowA * 256 + lk;

  f32x4 acc[16];
#pragma unroll
  for (int n = 0; n < 16; ++n) acc[n] = (f32x4){0.f, 0.f, 0.f, 0.f};

  for (int k0 = 0; k0 < 256; k0 += 32) {
    f32x4 a0 = *(const f32x4*)(hrow + k0);
    f32x4 a1 = *(const f32x4*)(hrow + k0 + 4);
    u16x8 au;
    au[0] = f2bf(a0[0]); au[1] = f2bf(a0[1]); au[2] = f2bf(a0[2]); au[3] = f2bf(a0[3]);
    au[4] = f2bf(a1[0]); au[5] = f2bf(a1[1]); au[6] = f2bf(a1[2]); au[7] = f2bf(a1[3]);
    bf16x8 af = __builtin_bit_cast(bf16x8, au);
#pragma unroll
    for (int n = 0; n < 16; ++n) {
      int4v bv = *(const int4v*)(WbT + (size_t)(16 * n + lr) * 256 + k0 + lk);
      bf16x8 bf = __builtin_bit_cast(bf16x8, bv);
      acc[n] = __builtin_amdgcn_mfma_f32_16x16x32_bf16(af, bf, acc[n], 0, 0, 0);
    }
  }
#pragma unroll
  for (int rr = 0; rr < 4; ++rr) {
    int row = bid * 64 + 16 * w + ((l >> 4) << 2) + rr;
    int bb = row >> 12, nl = row & 4095;
#pragma unroll
    for (int n = 0; n < 16; ++n) {
      int col = 16 * n + lr;
      float v = acc[n][rr];
      Hh[(size_t)row * 256 + col] = v;
      HhT[((size_t)(bb * 256 + col)) * 4096 + nl] = f2bf(v);
    }
  }
}

// ---------------- kernel 3: s,d per row (one wave per row) -----------
__global__ __launch_bounds__(256) void sdk(const float* __restrict__ Hh,
                                           const float* __restrict__ a,
                                           float* __restrict__ s,
                                           float* __restrict__ d) {
  int row = blockIdx.x * 4 + (threadIdx.x >> 6);
  int l = threadIdx.x & 63;
  f32x4 x  = *(const f32x4*)(Hh + (size_t)row * 256 + l * 4);
  f32x4 as = *(const f32x4*)(a + l * 4);
  f32x4 ad = *(const f32x4*)(a + 256 + l * 4);
  float sp = x[0] * as[0] + x[1] * as[1] + x[2] * as[2] + x[3] * as[3];
  float dp = x[0] * ad[0] + x[1] * ad[1] + x[2] * ad[2] + x[3] * ad[3];
#pragma unroll
  for (int off = 1; off < 64; off <<= 1) {
    sp += __shfl_xor(sp, off);
    dp += __shfl_xor(dp, off);
  }
  if (l == 0) { s[row] = sp; d[row] = dp; }
}

// ---------------- kernel 4: main fused GAT aggregation ----------------
// grid 256 (1/CU), block 256 thr / 4 waves; 64 rows x 256 cols per block.
// K-loop over neighbors m in steps of 32: e-tile generated on the fly.
__global__ __launch_bounds__(256) void gat_main(const int* __restrict__ adj,
                                                const u16* __restrict__ HhT,
                                                const float* __restrict__ s,
                                                const float* __restrict__ d,
                                                float* __restrict__ out) {
  __shared__ __align__(16) u16 At[64 * 40];    // e-tile, row stride 40 (2-way free)
  __shared__ __align__(16) u16 Bt[256 * 40];   // Hh^T tile [col][k]
  __shared__ float d_lds[4096];
  __shared__ float s_lds[64];
  __shared__ float rs_lds[64];

  const int tid = threadIdx.x;
  const int bid = blockIdx.x;
  // XCD swizzle: blocks round-robin XCDs (bid&7); give each batch 2 XCDs
  // so its 2MB HhT panel stays L2-resident.
  const int xcd = bid & 7;
  const int b = xcd >> 1;
  const int tile = (bid >> 3) + ((xcd & 1) << 5);
  const int rowbase = tile << 6;

  for (int i = tid; i < 4096; i += 256) d_lds[i] = d[b * 4096 + i];
  if (tid < 64) s_lds[tid] = s[b * 4096 + rowbase + tid];
  __syncthreads();

  const int l = tid & 63, w = tid >> 6;
  const int lr = l & 15, lk = (l >> 4) << 3;

  const int r = tid >> 2, q = tid & 3;     // e-gen: row r (0..63), k-quarter q
  const float s_row = s_lds[r];

  const int4v* aptr = (const int4v*)(adj + ((size_t)(b * 4096 + rowbase + r)) * 4096 + q * 8);
  const int4v* bptr0 = (const int4v*)(HhT + ((size_t)(b * 256 + r)) * 4096);
  const int4v* bptr1 = (const int4v*)(HhT + ((size_t)(b * 256 + r + 64)) * 4096);
  const int4v* bptr2 = (const int4v*)(HhT + ((size_t)(b * 256 + r + 128)) * 4096);
  const int4v* bptr3 = (const int4v*)(HhT + ((size_t)(b * 256 + r + 192)) * 4096);

  f32x4 acc[16];
#pragma unroll
  for (int n = 0; n < 16; ++n) acc[n] = (f32x4){0.f, 0.f, 0.f, 0.f};

  float rowacc = 0.f;

  // prologue prefetch (step 0)
  int4v pa0 = aptr[0], pa1 = aptr[1];
  int4v pb0 = bptr0[q], pb1 = bptr1[q], pb2 = bptr2[q], pb3 = bptr3[q];

  for (int step = 0; step < 128; ++step) {
    const int k0 = step << 5;
    __syncthreads();   // previous MFMA done reading LDS

    // ---- e generation: 8 values for (row r, m = k0 + q*8 + j) ----
    int aj[8] = {pa0.x, pa0.y, pa0.z, pa0.w, pa1.x, pa1.y, pa1.z, pa1.w};
    u16x8 ep;
#pragma unroll
    for (int j = 0; j < 8; ++j) {
      float lg = s_row + d_lds[k0 + q * 8 + j];
      float t = lg > 0.f ? lg : LRELU_ALPHA * lg;
      float e = (aj[j] != 0) ? __expf(-t) : 0.f;
      rowacc += e;
      ep[j] = f2bf(e);
    }
    *(int4v*)&At[r * 40 + q * 8] = __builtin_bit_cast(int4v, ep);

    // ---- stage Hh^T tile: thread handles 4 (col, k-quarter) cells ----
    *(int4v*)&At[0]; // no-op
    *(int4v*)&Bt[(r      ) * 40 + q * 8] = pb0;
    *(int4v*)&Bt[(r +  64) * 40 + q * 8] = pb1;
    *(int4v*)&Bt[(r + 128) * 40 + q * 8] = pb2;
    *(int4v*)&Bt[(r + 192) * 40 + q * 8] = pb3;

    // ---- prefetch next step into registers ----
    if (step < 127) {
      int ai = (step + 1) * 8;
      pa0 = aptr[ai]; pa1 = aptr[ai + 1];
      int bi = (step + 1) * 4 + q;
      pb0 = bptr0[bi]; pb1 = bptr1[bi]; pb2 = bptr2[bi]; pb3 = bptr3[bi];
    }
    __syncthreads();   // LDS tiles visible

    // ---- MFMA: wave w computes rows [16w,16w+16) x 256 cols ----
    bf16x8 af = __builtin_bit_cast(bf16x8, *(const int4v*)&At[(16 * w + lr) * 40 + lk]);
#pragma unroll
    for (int n = 0; n < 16; ++n) {
      bf16x8 bf = __builtin_bit_cast(bf16x8, *(const int4v*)&Bt[(16 * n + lr) * 40 + lk]);
      acc[n] = __builtin_amdgcn_mfma_f32_16x16x32_bf16(af, bf, acc[n], 0, 0, 0);
    }
  }

  // ---- rowsum: threads q=0..3 of each row hold disjoint partials ----
  float rsum = rowacc;
  rsum += __shfl_xor(rsum, 1);
  rsum += __shfl_xor(rsum, 2);
  if (q == 0) rs_lds[r] = (rsum == 0.f) ? 1.f : rsum;
  __syncthreads();

  // ---- epilogue: divide + elu + store ----
#pragma unroll
  for (int rr = 0; rr < 4; ++rr) {
    int rowin = ((l >> 4) << 2) + rr;
    float inv = 1.f / rs_lds[16 * w + rowin];
    size_t obase = ((size_t)(b * 4096 + rowbase + 16 * w + rowin)) * 256;
#pragma unroll
    for (int n = 0; n < 16; ++n) {
      float v = acc[n][rr] * inv;
      out[obase + 16 * n + lr] = v > 0.f ? v : (__expf(v) - 1.f);
    }
  }
}

extern "C" void kernel_launch(void* const* d_in, const int* in_sizes, int n_in,
                              void* d_out, int out_size, void* d_ws, size_t ws_size,
                              hipStream_t stream) {
  const float* h = (const float*)d_in[0];
  const int* adj = (const int*)d_in[1];
  const float* W = (const float*)d_in[2];
  const float* a = (const float*)d_in[3];
  float* out = (float*)d_out;

  // workspace layout
  u16* WbT   = (u16*)d_ws;                                         // 128 KB
  float* Hh  = (float*)((char*)d_ws + 131072);                     // 16 MB
  u16* HhT   = (u16*)((char*)d_ws + 131072 + 16777216);            // 8 MB
  float* sb  = (float*)((char*)d_ws + 131072 + 16777216 + 8388608);// 64 KB
  float* db  = sb + 16384;                                         // 64 KB

  hipLaunchKernelGGL(wcast,    dim3(256),  dim3(256), 0, stream, W, WbT);
  hipLaunchKernelGGL(gemm1,    dim3(256),  dim3(256), 0, stream, h, WbT, Hh, HhT);
  hipLaunchKernelGGL(sdk,      dim3(4096), dim3(256), 0, stream, Hh, a, sb, db);
  hipLaunchKernelGGL(gat_main, dim3(256),  dim3(256), 0, stream, adj, HhT, sb, db, out);
}

// Round 2
// 176.862 us; speedup vs baseline: 1.2757x; 1.2757x over previous
//
#include <hip/hip_runtime.h>

#define LRELU_ALPHA 0.2f

typedef __bf16 bf16x8 __attribute__((ext_vector_type(8)));
typedef unsigned short u16;
typedef unsigned short u16x4 __attribute__((ext_vector_type(4)));
typedef unsigned short u16x8 __attribute__((ext_vector_type(8)));
typedef unsigned int   u32x2 __attribute__((ext_vector_type(2)));
typedef float f32x4 __attribute__((ext_vector_type(4)));
typedef int int4v __attribute__((ext_vector_type(4)));

__device__ __forceinline__ u16 f2bf(float f) {
  unsigned int u = __float_as_uint(f);
  u += 0x7fffu + ((u >> 16) & 1u);   // RNE
  return (u16)(u >> 16);
}

// ---------------- kernel 1: WbT[o][i] = bf16(W[i][o]) ----------------
__global__ __launch_bounds__(256) void wcast(const float* __restrict__ W,
                                             u16* __restrict__ WbT) {
  int idx = blockIdx.x * 256 + threadIdx.x;            // 65536
  WbT[idx] = f2bf(W[(idx & 255) * 256 + (idx >> 8)]);
}

// ---------------- kernel 2: Hh = bf16(h) @ W, fused s/d dots ----------
// block: 256 thr / 4 waves, 64 rows x 256 cols per block, grid 256.
// Writes HhT bf16 (transposed) + s,d per row. No f32 Hh buffer.
__global__ __launch_bounds__(256) void gemm1(const float* __restrict__ h,
                                             const u16* __restrict__ WbT,
                                             const float* __restrict__ a,
                                             u16* __restrict__ HhT,
                                             float* __restrict__ sbuf,
                                             float* __restrict__ dbuf) {
  const int tid = threadIdx.x, bid = blockIdx.x;
  const int l = tid & 63, w = tid >> 6;
  const int lr = l & 15;              // frag row (A) / col (B)
  const int lk = (l >> 4) << 3;       // k offset within 32
  const int rowA = bid * 64 + 16 * w + lr;
  const float* hrow = h + (size_t)rowA * 256 + lk;

  f32x4 acc[16];
#pragma unroll
  for (int n = 0; n < 16; ++n) acc[n] = (f32x4){0.f, 0.f, 0.f, 0.f};

  for (int k0 = 0; k0 < 256; k0 += 32) {
    f32x4 a0 = *(const f32x4*)(hrow + k0);
    f32x4 a1 = *(const f32x4*)(hrow + k0 + 4);
    u16x8 au;
    au[0] = f2bf(a0[0]); au[1] = f2bf(a0[1]); au[2] = f2bf(a0[2]); au[3] = f2bf(a0[3]);
    au[4] = f2bf(a1[0]); au[5] = f2bf(a1[1]); au[6] = f2bf(a1[2]); au[7] = f2bf(a1[3]);
    bf16x8 af = __builtin_bit_cast(bf16x8, au);
#pragma unroll
    for (int n = 0; n < 16; ++n) {
      int4v bv = *(const int4v*)(WbT + (size_t)(16 * n + lr) * 256 + k0 + lk);
      bf16x8 bf = __builtin_bit_cast(bf16x8, bv);
      acc[n] = __builtin_amdgcn_mfma_f32_16x16x32_bf16(af, bf, acc[n], 0, 0, 0);
    }
  }

  // HhT write + fused s,d dot products
  float sp[4] = {0.f, 0.f, 0.f, 0.f}, dp[4] = {0.f, 0.f, 0.f, 0.f};
#pragma unroll
  for (int n = 0; n < 16; ++n) {
    int col = 16 * n + lr;
    float as = a[col];
    float ad = a[256 + col];
#pragma unroll
    for (int rr = 0; rr < 4; ++rr) {
      int row = bid * 64 + 16 * w + ((l >> 4) << 2) + rr;
      int bb = row >> 12, nl = row & 4095;
      float v = acc[n][rr];
      HhT[((size_t)(bb * 256 + col)) * 4096 + nl] = f2bf(v);
      sp[rr] += v * as;
      dp[rr] += v * ad;
    }
  }
#pragma unroll
  for (int rr = 0; rr < 4; ++rr) {
#pragma unroll
    for (int off = 1; off < 16; off <<= 1) {
      sp[rr] += __shfl_xor(sp[rr], off);
      dp[rr] += __shfl_xor(dp[rr], off);
    }
  }
  if ((l & 15) == 0) {
#pragma unroll
    for (int rr = 0; rr < 4; ++rr) {
      int row = bid * 64 + 16 * w + ((l >> 4) << 2) + rr;
      sbuf[row] = sp[rr];
      dbuf[row] = dp[rr];
    }
  }
}

// ---------------- kernel 3: main fused GAT aggregation ----------------
// grid 512 (2/CU), block 256 thr / 4 waves; 32 rows x 256 cols per block.
// Double-buffered LDS, raw s_barrier (lgkm-only drain), depth-2 reg prefetch.
__global__ __launch_bounds__(256, 2) void gat_main(const int* __restrict__ adj,
                                                   const u16* __restrict__ HhT,
                                                   const float* __restrict__ s,
                                                   const float* __restrict__ d,
                                                   float* __restrict__ out) {
  __shared__ __align__(16) u16 At[2][32 * 40];    // e-tile, stride 40 (2-way free)
  __shared__ __align__(16) u16 Bt[2][256 * 40];   // Hh^T tile [col][k]
  __shared__ float d_lds[4096];
  __shared__ float rs_lds[32];

  const int tid = threadIdx.x;
  const int bid = blockIdx.x;
  // XCD swizzle: 512 blocks, xcd = bid&7; batch b gets 2 XCDs so its
  // 2MB HhT panel stays L2-resident.
  const int xcd = bid & 7;
  const int b = xcd >> 1;
  const int tile = (bid >> 3) | ((xcd & 1) << 6);   // 0..127
  const int rowbase = tile << 5;

  for (int i = tid; i < 4096; i += 256) d_lds[i] = d[b * 4096 + i];

  const int r = tid >> 3, q = tid & 7;     // e-gen: row r (0..31), q-octant
  const float s_row = s[b * 4096 + rowbase + r];

  // adj: int4 per (r, step, q): element (step*8 + q)
  const int4v* aptr = (const int4v*)(adj + ((size_t)(b * 4096 + rowbase + r)) * 4096);
  // HhT staging: thread covers cols cr, cr+64, cr+128, cr+192, chunk cp
  const int cr = tid >> 2, cp = tid & 3;
  const int4v* bp0 = (const int4v*)HhT + (((size_t)(b * 256 + cr      )) << 9) + cp;
  const int4v* bp1 = (const int4v*)HhT + (((size_t)(b * 256 + cr +  64)) << 9) + cp;
  const int4v* bp2 = (const int4v*)HhT + (((size_t)(b * 256 + cr + 128)) << 9) + cp;
  const int4v* bp3 = (const int4v*)HhT + (((size_t)(b * 256 + cr + 192)) << 9) + cp;

  const int l = tid & 63, w = tid >> 6;
  const int lr = l & 15, lk = (l >> 4) << 3;
  const int row0 = 16 * (w & 1);
  const int colb = 128 * (w >> 1);

  f32x4 acc[8];
#pragma unroll
  for (int n = 0; n < 8; ++n) acc[n] = (f32x4){0.f, 0.f, 0.f, 0.f};
  float rowacc = 0.f;

  __syncthreads();   // d_lds ready (full drain OK once, in prologue)

  // depth-2 prefetch: set A = even step, set B = odd step
  int4v pa_a = aptr[q],        pa_b = aptr[8 + q];
  int4v pb0_a = bp0[0], pb1_a = bp1[0], pb2_a = bp2[0], pb3_a = bp3[0];
  int4v pb0_b = bp0[4], pb1_b = bp1[4], pb2_b = bp2[4], pb3_b = bp3[4];

#define SUBSTEP(BUF, PA, PB0, PB1, PB2, PB3, CURSTEP, NEXTSTEP)               \
  {                                                                           \
    const int k0_ = (CURSTEP) << 5;                                           \
    f32x4 dv = *(const f32x4*)&d_lds[k0_ + q * 4];                            \
    int aj[4] = {PA.x, PA.y, PA.z, PA.w};                                     \
    u16x4 ep;                                                                 \
    _Pragma("unroll")                                                         \
    for (int j = 0; j < 4; ++j) {                                             \
      float lg = s_row + dv[j];                                               \
      float t = lg > 0.f ? lg : LRELU_ALPHA * lg;                             \
      float e = (aj[j] != 0) ? __expf(-t) : 0.f;                              \
      rowacc += e;                                                            \
      ep[j] = f2bf(e);                                                        \
    }                                                                         \
    *(u32x2*)&At[BUF][r * 40 + q * 4] = __builtin_bit_cast(u32x2, ep);        \
    *(int4v*)&Bt[BUF][(cr      ) * 40 + cp * 8] = PB0;                        \
    *(int4v*)&Bt[BUF][(cr +  64) * 40 + cp * 8] = PB1;                        \
    *(int4v*)&Bt[BUF][(cr + 128) * 40 + cp * 8] = PB2;                        \
    *(int4v*)&Bt[BUF][(cr + 192) * 40 + cp * 8] = PB3;                        \
    {                                                                         \
      const int ns_ = (NEXTSTEP);                                             \
      PA  = aptr[ns_ * 8 + q];                                                \
      PB0 = bp0[ns_ << 2];                                                    \
      PB1 = bp1[ns_ << 2];                                                    \
      PB2 = bp2[ns_ << 2];                                                    \
      PB3 = bp3[ns_ << 2];                                                    \
    }                                                                         \
    asm volatile("s_waitcnt lgkmcnt(0)" ::: "memory");                        \
    __builtin_amdgcn_s_barrier();                                             \
    {                                                                         \
      bf16x8 af = __builtin_bit_cast(bf16x8,                                  \
          *(const int4v*)&At[BUF][(row0 + lr) * 40 + lk]);                    \
      _Pragma("unroll")                                                       \
      for (int n = 0; n < 8; ++n) {                                           \
        bf16x8 bf = __builtin_bit_cast(bf16x8,                                \
            *(const int4v*)&Bt[BUF][(colb + 16 * n + lr) * 40 + lk]);         \
        acc[n] = __builtin_amdgcn_mfma_f32_16x16x32_bf16(af, bf, acc[n],      \
                                                         0, 0, 0);            \
      }                                                                       \
    }                                                                         \
  }

  for (int sp2 = 0; sp2 < 128; sp2 += 2) {
    int na = sp2 + 2; if (na > 127) na = 127;   // clamped (redundant) prefetch
    int nb = sp2 + 3; if (nb > 127) nb = 127;
    SUBSTEP(0, pa_a, pb0_a, pb1_a, pb2_a, pb3_a, sp2, na)
    SUBSTEP(1, pa_b, pb0_b, pb1_b, pb2_b, pb3_b, sp2 + 1, nb)
  }
#undef SUBSTEP

  // ---- rowsum: 8 q-threads per row hold disjoint partials ----
  float rsum = rowacc;
  rsum += __shfl_xor(rsum, 1);
  rsum += __shfl_xor(rsum, 2);
  rsum += __shfl_xor(rsum, 4);
  if (q == 0) rs_lds[r] = (rsum == 0.f) ? 1.f : rsum;
  __syncthreads();

  // ---- epilogue: divide + elu + store ----
#pragma unroll
  for (int rr = 0; rr < 4; ++rr) {
    int rin = row0 + ((l >> 4) << 2) + rr;
    float inv = 1.f / rs_lds[rin];
    size_t obase = ((size_t)(b * 4096 + rowbase + rin)) * 256 + colb;
#pragma unroll
    for (int n = 0; n < 8; ++n) {
      float v = acc[n][rr] * inv;
      out[obase + 16 * n + lr] = v > 0.f ? v : (__expf(v) - 1.f);
    }
  }
}

extern "C" void kernel_launch(void* const* d_in, const int* in_sizes, int n_in,
                              void* d_out, int out_size, void* d_ws, size_t ws_size,
                              hipStream_t stream) {
  const float* h = (const float*)d_in[0];
  const int* adj = (const int*)d_in[1];
  const float* W = (const float*)d_in[2];
  const float* a = (const float*)d_in[3];
  float* out = (float*)d_out;

  // workspace layout
  u16* WbT  = (u16*)d_ws;                                  // 128 KB
  u16* HhT  = (u16*)((char*)d_ws + 131072);                // 8 MB
  float* sb = (float*)((char*)d_ws + 131072 + 8388608);    // 64 KB
  float* db = sb + 16384;                                  // 64 KB

  hipLaunchKernelGGL(wcast,    dim3(256), dim3(256), 0, stream, W, WbT);
  hipLaunchKernelGGL(gemm1,    dim3(256), dim3(256), 0, stream, h, WbT, a, HhT, sb, db);
  hipLaunchKernelGGL(gat_main, dim3(512), dim3(256), 0, stream, adj, HhT, sb, db, out);
}